// Round 1
// baseline (171.147 us; speedup 1.0000x reference)
//
#include <hip/hip_runtime.h>

#define N_ROWS 8192
#define DIM 256
#define EPSF 1e-8f

// ---------------------------------------------------------------------------
// K1: per-row inv_norm (fp32) + column sums of x_hat accumulated in fp64.
// One wave (64 lanes) per row; lane owns 4 contiguous columns (float4).
// ---------------------------------------------------------------------------
__global__ __launch_bounds__(256) void k1_norm_s(const float* __restrict__ T,
                                                 float* __restrict__ inv_norm,
                                                 double* __restrict__ s) {
    __shared__ double sacc[4][DIM];
    const int lane = threadIdx.x & 63;
    const int wave = threadIdx.x >> 6;
    const int gw = blockIdx.x * 4 + wave;
    const int nw = gridDim.x * 4;
    double a0 = 0.0, a1 = 0.0, a2 = 0.0, a3 = 0.0;
    for (int row = gw; row < N_ROWS; row += nw) {
        float4 v = ((const float4*)(T + (size_t)row * DIM))[lane];
        float ss = v.x * v.x + v.y * v.y + v.z * v.z + v.w * v.w;
#pragma unroll
        for (int o = 32; o; o >>= 1) ss += __shfl_down(ss, o);
        ss = __shfl(ss, 0);
        float inv = 1.0f / fmaxf(sqrtf(ss), EPSF);
        if (lane == 0) inv_norm[row] = inv;
        a0 += (double)(v.x * inv);
        a1 += (double)(v.y * inv);
        a2 += (double)(v.z * inv);
        a3 += (double)(v.w * inv);
    }
    sacc[wave][lane * 4 + 0] = a0;
    sacc[wave][lane * 4 + 1] = a1;
    sacc[wave][lane * 4 + 2] = a2;
    sacc[wave][lane * 4 + 3] = a3;
    __syncthreads();
    const int tid = threadIdx.x;
    double t = sacc[0][tid] + sacc[1][tid] + sacc[2][tid] + sacc[3][tid];
    atomicAdd(&s[tid], t);
}

// ---------------------------------------------------------------------------
// K2b: row_sum[i] = inv_norm[i] * dot(T[i,:], s)  in fp64 (precision-critical).
// ---------------------------------------------------------------------------
__global__ __launch_bounds__(256) void k2_rowsum(const float* __restrict__ T,
                                                 const float* __restrict__ inv_norm,
                                                 const double* __restrict__ s,
                                                 double* __restrict__ rs) {
    const int lane = threadIdx.x & 63;
    const int wave = threadIdx.x >> 6;
    const int gw = blockIdx.x * 4 + wave;
    const int nw = gridDim.x * 4;
    const double s0 = s[lane * 4 + 0];
    const double s1 = s[lane * 4 + 1];
    const double s2 = s[lane * 4 + 2];
    const double s3 = s[lane * 4 + 3];
    for (int row = gw; row < N_ROWS; row += nw) {
        float4 v = ((const float4*)(T + (size_t)row * DIM))[lane];
        double d = (double)v.x * s0 + (double)v.y * s1 + (double)v.z * s2 + (double)v.w * s3;
#pragma unroll
        for (int o = 32; o; o >>= 1) d += __shfl_down(d, o);
        if (lane == 0) rs[row] = d * (double)inv_norm[row];
    }
}

// ---------------------------------------------------------------------------
// K2: M[k][d] = sum_i x_hat[i][k] * T[i][d].  256x256 output, K=8192.
// grid (4,4,32): 64x64 output tile, 256-row split-K chunk, fp32 atomics out.
// ---------------------------------------------------------------------------
__global__ __launch_bounds__(256) void k_gemmM(const float* __restrict__ T,
                                               const float* __restrict__ inv_norm,
                                               float* __restrict__ M) {
    const int k0 = blockIdx.x * 64;
    const int d0 = blockIdx.y * 64;
    const int i0 = blockIdx.z * 256;
    __shared__ float As[32][68];
    __shared__ float Bs[32][68];
    const int tid = threadIdx.x;
    const int tx = tid & 15, ty = tid >> 4;
    float acc[4][4] = {};
    for (int ic = 0; ic < 256; ic += 32) {
        for (int t = tid; t < 512; t += 256) {
            int r = t >> 4, c4 = (t & 15) * 4;
            int gi = i0 + ic + r;
            float inv = inv_norm[gi];
            const float* rowp = T + (size_t)gi * DIM;
            float4 a = *(const float4*)(rowp + k0 + c4);
            a.x *= inv; a.y *= inv; a.z *= inv; a.w *= inv;
            *(float4*)&As[r][c4] = a;
            *(float4*)&Bs[r][c4] = *(const float4*)(rowp + d0 + c4);
        }
        __syncthreads();
#pragma unroll
        for (int ii = 0; ii < 32; ++ii) {
            float4 av = *(const float4*)&As[ii][ty * 4];
            float4 bv = *(const float4*)&Bs[ii][tx * 4];
            float a[4] = {av.x, av.y, av.z, av.w};
            float b[4] = {bv.x, bv.y, bv.z, bv.w};
#pragma unroll
            for (int p = 0; p < 4; ++p)
#pragma unroll
                for (int q = 0; q < 4; ++q)
                    acc[p][q] = fmaf(a[p], b[q], acc[p][q]);
        }
        __syncthreads();
    }
#pragma unroll
    for (int p = 0; p < 4; ++p)
#pragma unroll
        for (int q = 0; q < 4; ++q)
            atomicAdd(&M[(size_t)(k0 + ty * 4 + p) * DIM + d0 + tx * 4 + q],
                      acc[p][q]);
}

// ---------------------------------------------------------------------------
// K3: out[i][d] = (x_hat[i,:] @ M[:,d]) / rs[i].
// grid (128,4): 64 rows x 64 cols per block, 4x4 per thread, K=256 in LDS chunks.
// ---------------------------------------------------------------------------
__global__ __launch_bounds__(256) void k3_out(const float* __restrict__ T,
                                              const float* __restrict__ inv_norm,
                                              const float* __restrict__ M,
                                              const double* __restrict__ rs,
                                              float* __restrict__ out) {
    const int i0 = blockIdx.x * 64;
    const int d0 = blockIdx.y * 64;
    __shared__ float Xs[32][68];  // [kk][ii]
    __shared__ float Ms[32][68];  // [kk][dd]
    const int tid = threadIdx.x;
    const int tx = tid & 15, ty = tid >> 4;
    float acc[4][4] = {};
    for (int kc = 0; kc < 256; kc += 32) {
        for (int t = tid; t < 512; t += 256) {
            int ii = t >> 3, k4 = (t & 7) * 4;
            int gi = i0 + ii;
            float inv = inv_norm[gi];
            float4 v = *(const float4*)(T + (size_t)gi * DIM + kc + k4);
            Xs[k4 + 0][ii] = v.x * inv;
            Xs[k4 + 1][ii] = v.y * inv;
            Xs[k4 + 2][ii] = v.z * inv;
            Xs[k4 + 3][ii] = v.w * inv;
        }
        for (int t = tid; t < 512; t += 256) {
            int kk = t >> 4, d4 = (t & 15) * 4;
            *(float4*)&Ms[kk][d4] = *(const float4*)(M + (size_t)(kc + kk) * DIM + d0 + d4);
        }
        __syncthreads();
#pragma unroll
        for (int kk = 0; kk < 32; ++kk) {
            float4 av = *(const float4*)&Xs[kk][ty * 4];
            float4 bv = *(const float4*)&Ms[kk][tx * 4];
            float a[4] = {av.x, av.y, av.z, av.w};
            float b[4] = {bv.x, bv.y, bv.z, bv.w};
#pragma unroll
            for (int p = 0; p < 4; ++p)
#pragma unroll
                for (int q = 0; q < 4; ++q)
                    acc[p][q] = fmaf(a[p], b[q], acc[p][q]);
        }
        __syncthreads();
    }
#pragma unroll
    for (int p = 0; p < 4; ++p) {
        int gi = i0 + ty * 4 + p;
        float invr = (float)(1.0 / rs[gi]);
        float4 o;
        o.x = acc[p][0] * invr;
        o.y = acc[p][1] * invr;
        o.z = acc[p][2] * invr;
        o.w = acc[p][3] * invr;
        *(float4*)(out + (size_t)gi * DIM + d0 + tx * 4) = o;
    }
}

// ---------------------------------------------------------------------------
extern "C" void kernel_launch(void* const* d_in, const int* in_sizes, int n_in,
                              void* d_out, int out_size, void* d_ws, size_t ws_size,
                              hipStream_t stream) {
    const float* T = (const float*)d_in[0];
    float* out = (float*)d_out;

    // workspace layout (all 16B-aligned):
    //   [0, 32768)        inv_norm  float[8192]
    //   [32768, 34816)    s         double[256]
    //   [34816, 100352)   rs        double[8192]
    //   [100352, 362496)  M         float[256*256]
    char* ws = (char*)d_ws;
    float* inv_norm = (float*)(ws);
    double* s = (double*)(ws + 32768);
    double* rs = (double*)(ws + 34816);
    float* M = (float*)(ws + 100352);

    hipMemsetAsync(s, 0, 256 * sizeof(double), stream);
    hipMemsetAsync(M, 0, DIM * DIM * sizeof(float), stream);

    k1_norm_s<<<64, 256, 0, stream>>>(T, inv_norm, s);
    k2_rowsum<<<64, 256, 0, stream>>>(T, inv_norm, s, rs);
    k_gemmM<<<dim3(4, 4, 32), 256, 0, stream>>>(T, inv_norm, M);
    k3_out<<<dim3(128, 4), 256, 0, stream>>>(T, inv_norm, M, rs, out);
}

// Round 2
// 121.750 us; speedup vs baseline: 1.4057x; 1.4057x over previous
//
#include <hip/hip_runtime.h>

#define N_ROWS 8192
#define DIM 256
#define EPSF 1e-8f

// ---------------------------------------------------------------------------
// K1: per-row inv_norm (fp32) + column sums of x_hat accumulated in fp64.
// One wave (64 lanes) per row; lane owns 4 contiguous columns (float4).
// ---------------------------------------------------------------------------
__global__ __launch_bounds__(256) void k1_norm_s(const float* __restrict__ T,
                                                 float* __restrict__ inv_norm,
                                                 double* __restrict__ s) {
    __shared__ double sacc[4][DIM];
    const int lane = threadIdx.x & 63;
    const int wave = threadIdx.x >> 6;
    const int gw = blockIdx.x * 4 + wave;
    const int nw = gridDim.x * 4;
    double a0 = 0.0, a1 = 0.0, a2 = 0.0, a3 = 0.0;
    for (int row = gw; row < N_ROWS; row += nw) {
        float4 v = ((const float4*)(T + (size_t)row * DIM))[lane];
        float ss = v.x * v.x + v.y * v.y + v.z * v.z + v.w * v.w;
#pragma unroll
        for (int o = 32; o; o >>= 1) ss += __shfl_down(ss, o);
        ss = __shfl(ss, 0);
        float inv = 1.0f / fmaxf(sqrtf(ss), EPSF);
        if (lane == 0) inv_norm[row] = inv;
        a0 += (double)(v.x * inv);
        a1 += (double)(v.y * inv);
        a2 += (double)(v.z * inv);
        a3 += (double)(v.w * inv);
    }
    sacc[wave][lane * 4 + 0] = a0;
    sacc[wave][lane * 4 + 1] = a1;
    sacc[wave][lane * 4 + 2] = a2;
    sacc[wave][lane * 4 + 3] = a3;
    __syncthreads();
    const int tid = threadIdx.x;
    double t = sacc[0][tid] + sacc[1][tid] + sacc[2][tid] + sacc[3][tid];
    atomicAdd(&s[tid], t);
}

// ---------------------------------------------------------------------------
// K2b: row_sum[i] = inv_norm[i] * dot(T[i,:], s)  in fp64 (precision-critical).
// ---------------------------------------------------------------------------
__global__ __launch_bounds__(256) void k2_rowsum(const float* __restrict__ T,
                                                 const float* __restrict__ inv_norm,
                                                 const double* __restrict__ s,
                                                 double* __restrict__ rs) {
    const int lane = threadIdx.x & 63;
    const int wave = threadIdx.x >> 6;
    const int gw = blockIdx.x * 4 + wave;
    const int nw = gridDim.x * 4;
    const double s0 = s[lane * 4 + 0];
    const double s1 = s[lane * 4 + 1];
    const double s2 = s[lane * 4 + 2];
    const double s3 = s[lane * 4 + 3];
    for (int row = gw; row < N_ROWS; row += nw) {
        float4 v = ((const float4*)(T + (size_t)row * DIM))[lane];
        double d = (double)v.x * s0 + (double)v.y * s1 + (double)v.z * s2 + (double)v.w * s3;
#pragma unroll
        for (int o = 32; o; o >>= 1) d += __shfl_down(d, o);
        if (lane == 0) rs[row] = d * (double)inv_norm[row];
    }
}

// ---------------------------------------------------------------------------
// Stage-1 of M = X_hat^T @ T: 64x64 tile per block, 256-row K-slab, reg-staged
// pipelined LDS (issue next chunk's global loads before computing current),
// writes fp32 partial tile to ws (NO atomics — atomics write through to HBM
// at 16 B each, measured 33 MB last round).
// ---------------------------------------------------------------------------
__global__ __launch_bounds__(256) void k_gemmM_p(const float* __restrict__ T,
                                                 const float* __restrict__ inv_norm,
                                                 float* __restrict__ partials) {
    const int k0 = blockIdx.x * 64;
    const int d0 = blockIdx.y * 64;
    const int i0 = blockIdx.z * 256;
    __shared__ float As[32][68];
    __shared__ float Bs[32][68];
    const int tid = threadIdx.x;
    const int tx = tid & 15, ty = tid >> 4;
    float acc[4][4] = {};
    float4 ra[2], rb[2];
    float rinv[2];

    auto stage = [&](int ic) {
#pragma unroll
        for (int j = 0; j < 2; ++j) {
            int t = tid + 256 * j;
            int r = t >> 4, c4 = (t & 15) * 4;
            int gi = i0 + ic + r;
            rinv[j] = inv_norm[gi];
            const float* rowp = T + (size_t)gi * DIM;
            ra[j] = *(const float4*)(rowp + k0 + c4);
            rb[j] = *(const float4*)(rowp + d0 + c4);
        }
    };
    auto commit = [&]() {
#pragma unroll
        for (int j = 0; j < 2; ++j) {
            int t = tid + 256 * j;
            int r = t >> 4, c4 = (t & 15) * 4;
            float4 a = ra[j];
            float inv = rinv[j];
            a.x *= inv; a.y *= inv; a.z *= inv; a.w *= inv;
            *(float4*)&As[r][c4] = a;
            *(float4*)&Bs[r][c4] = rb[j];
        }
    };
    auto compute = [&]() {
#pragma unroll
        for (int ii = 0; ii < 32; ++ii) {
            float4 av = *(const float4*)&As[ii][ty * 4];
            float4 bv = *(const float4*)&Bs[ii][tx * 4];
            float a[4] = {av.x, av.y, av.z, av.w};
            float b[4] = {bv.x, bv.y, bv.z, bv.w};
#pragma unroll
            for (int p = 0; p < 4; ++p)
#pragma unroll
                for (int q = 0; q < 4; ++q)
                    acc[p][q] = fmaf(a[p], b[q], acc[p][q]);
        }
    };

    stage(0);
    commit();
    __syncthreads();
    for (int ic = 32; ic < 256; ic += 32) {
        stage(ic);       // global loads for next chunk in flight...
        compute();       // ...while we compute the current LDS chunk
        __syncthreads();
        commit();
        __syncthreads();
    }
    compute();

    float* pt = partials +
        (size_t)(blockIdx.z * 16 + blockIdx.y * 4 + blockIdx.x) * 4096;
#pragma unroll
    for (int p = 0; p < 4; ++p) {
        float4 o = make_float4(acc[p][0], acc[p][1], acc[p][2], acc[p][3]);
        *(float4*)(pt + (ty * 4 + p) * 64 + tx * 4) = o;
    }
}

// ---------------------------------------------------------------------------
// Stage-2: M[k][d] = sum over 32 z-slabs of the partial tiles.
// ---------------------------------------------------------------------------
__global__ __launch_bounds__(256) void k_reduceM(const float* __restrict__ partials,
                                                 float* __restrict__ M) {
    const int g = blockIdx.x * 256 + threadIdx.x;  // 0..65535
    const int k = g >> 8, d = g & 255;
    const float* p = partials + (size_t)((d >> 6) * 4 + (k >> 6)) * 4096 +
                     (size_t)(k & 63) * 64 + (d & 63);
    float a0 = 0.f, a1 = 0.f, a2 = 0.f, a3 = 0.f;
#pragma unroll
    for (int z = 0; z < 32; z += 4) {
        a0 += p[(size_t)(z + 0) * 65536];
        a1 += p[(size_t)(z + 1) * 65536];
        a2 += p[(size_t)(z + 2) * 65536];
        a3 += p[(size_t)(z + 3) * 65536];
    }
    M[g] = (a0 + a1) + (a2 + a3);
}

// ---------------------------------------------------------------------------
// Fallback stage for tiny ws: original atomic version (correct, slower).
// ---------------------------------------------------------------------------
__global__ __launch_bounds__(256) void k_gemmM_atomic(const float* __restrict__ T,
                                                      const float* __restrict__ inv_norm,
                                                      float* __restrict__ M) {
    const int k0 = blockIdx.x * 64;
    const int d0 = blockIdx.y * 64;
    const int i0 = blockIdx.z * 256;
    __shared__ float As[32][68];
    __shared__ float Bs[32][68];
    const int tid = threadIdx.x;
    const int tx = tid & 15, ty = tid >> 4;
    float acc[4][4] = {};
    for (int ic = 0; ic < 256; ic += 32) {
        for (int t = tid; t < 512; t += 256) {
            int r = t >> 4, c4 = (t & 15) * 4;
            int gi = i0 + ic + r;
            float inv = inv_norm[gi];
            const float* rowp = T + (size_t)gi * DIM;
            float4 a = *(const float4*)(rowp + k0 + c4);
            a.x *= inv; a.y *= inv; a.z *= inv; a.w *= inv;
            *(float4*)&As[r][c4] = a;
            *(float4*)&Bs[r][c4] = *(const float4*)(rowp + d0 + c4);
        }
        __syncthreads();
#pragma unroll
        for (int ii = 0; ii < 32; ++ii) {
            float4 av = *(const float4*)&As[ii][ty * 4];
            float4 bv = *(const float4*)&Bs[ii][tx * 4];
            float a[4] = {av.x, av.y, av.z, av.w};
            float b[4] = {bv.x, bv.y, bv.z, bv.w};
#pragma unroll
            for (int p = 0; p < 4; ++p)
#pragma unroll
                for (int q = 0; q < 4; ++q)
                    acc[p][q] = fmaf(a[p], b[q], acc[p][q]);
        }
        __syncthreads();
    }
#pragma unroll
    for (int p = 0; p < 4; ++p)
#pragma unroll
        for (int q = 0; q < 4; ++q)
            atomicAdd(&M[(size_t)(k0 + ty * 4 + p) * DIM + d0 + tx * 4 + q],
                      acc[p][q]);
}

// ---------------------------------------------------------------------------
// K3: out[i][d] = (x_hat[i,:] @ M[:,d]) / rs[i], reg-staged pipelined.
// ---------------------------------------------------------------------------
__global__ __launch_bounds__(256) void k3_out(const float* __restrict__ T,
                                              const float* __restrict__ inv_norm,
                                              const float* __restrict__ M,
                                              const double* __restrict__ rs,
                                              float* __restrict__ out) {
    const int i0 = blockIdx.x * 64;
    const int d0 = blockIdx.y * 64;
    __shared__ float Xs[32][68];  // [kk][ii]
    __shared__ float Ms[32][68];  // [kk][dd]
    const int tid = threadIdx.x;
    const int tx = tid & 15, ty = tid >> 4;
    float acc[4][4] = {};
    float4 rx[2], rm[2];
    float rinv[2];

    auto stage = [&](int kc) {
#pragma unroll
        for (int j = 0; j < 2; ++j) {
            int t = tid + 256 * j;
            int ii = t >> 3, k4 = (t & 7) * 4;
            int gi = i0 + ii;
            rinv[j] = inv_norm[gi];
            rx[j] = *(const float4*)(T + (size_t)gi * DIM + kc + k4);
            int kk = t >> 4, d4 = (t & 15) * 4;
            rm[j] = *(const float4*)(M + (size_t)(kc + kk) * DIM + d0 + d4);
        }
    };
    auto commit = [&]() {
#pragma unroll
        for (int j = 0; j < 2; ++j) {
            int t = tid + 256 * j;
            int ii = t >> 3, k4 = (t & 7) * 4;
            float inv = rinv[j];
            Xs[k4 + 0][ii] = rx[j].x * inv;
            Xs[k4 + 1][ii] = rx[j].y * inv;
            Xs[k4 + 2][ii] = rx[j].z * inv;
            Xs[k4 + 3][ii] = rx[j].w * inv;
            int kk = t >> 4, d4 = (t & 15) * 4;
            *(float4*)&Ms[kk][d4] = rm[j];
        }
    };
    auto compute = [&]() {
#pragma unroll
        for (int kk = 0; kk < 32; ++kk) {
            float4 av = *(const float4*)&Xs[kk][ty * 4];
            float4 bv = *(const float4*)&Ms[kk][tx * 4];
            float a[4] = {av.x, av.y, av.z, av.w};
            float b[4] = {bv.x, bv.y, bv.z, bv.w};
#pragma unroll
            for (int p = 0; p < 4; ++p)
#pragma unroll
                for (int q = 0; q < 4; ++q)
                    acc[p][q] = fmaf(a[p], b[q], acc[p][q]);
        }
    };

    stage(0);
    commit();
    __syncthreads();
    for (int kc = 32; kc < 256; kc += 32) {
        stage(kc);
        compute();
        __syncthreads();
        commit();
        __syncthreads();
    }
    compute();

#pragma unroll
    for (int p = 0; p < 4; ++p) {
        int gi = i0 + ty * 4 + p;
        float invr = (float)(1.0 / rs[gi]);
        float4 o;
        o.x = acc[p][0] * invr;
        o.y = acc[p][1] * invr;
        o.z = acc[p][2] * invr;
        o.w = acc[p][3] * invr;
        *(float4*)(out + (size_t)gi * DIM + d0 + tx * 4) = o;
    }
}

// ---------------------------------------------------------------------------
extern "C" void kernel_launch(void* const* d_in, const int* in_sizes, int n_in,
                              void* d_out, int out_size, void* d_ws, size_t ws_size,
                              hipStream_t stream) {
    const float* T = (const float*)d_in[0];
    float* out = (float*)d_out;

    // workspace layout (all 16B-aligned):
    //   [0, 32768)          inv_norm  float[8192]
    //   [32768, 34816)      s         double[256]
    //   [34816, 100352)     rs        double[8192]
    //   [100352, 362496)    M         float[256*256]
    //   [362496, 8751104)   partials  float[32*16*4096]   (8 MB, optional)
    char* ws = (char*)d_ws;
    float* inv_norm = (float*)(ws);
    double* s = (double*)(ws + 32768);
    double* rs = (double*)(ws + 34816);
    float* M = (float*)(ws + 100352);
    float* partials = (float*)(ws + 362496);
    const bool use_partials = ws_size >= (size_t)362496 + 32ull * 16 * 4096 * 4;

    hipMemsetAsync(s, 0, 256 * sizeof(double), stream);

    k1_norm_s<<<128, 256, 0, stream>>>(T, inv_norm, s);
    k2_rowsum<<<256, 256, 0, stream>>>(T, inv_norm, s, rs);
    if (use_partials) {
        k_gemmM_p<<<dim3(4, 4, 32), 256, 0, stream>>>(T, inv_norm, partials);
        k_reduceM<<<256, 256, 0, stream>>>(partials, M);
    } else {
        hipMemsetAsync(M, 0, DIM * DIM * sizeof(float), stream);
        k_gemmM_atomic<<<dim3(4, 4, 32), 256, 0, stream>>>(T, inv_norm, M);
    }
    k3_out<<<dim3(128, 4), 256, 0, stream>>>(T, inv_norm, M, rs, out);
}

// Round 3
// 120.678 us; speedup vs baseline: 1.4182x; 1.0089x over previous
//
#include <hip/hip_runtime.h>

#define N_ROWS 8192
#define DIM 256
#define EPSF 1e-8f

// ---------------------------------------------------------------------------
// K1: per-row inv_norm (fp32) + column sums of x_hat accumulated in fp64.
// One wave (64 lanes) per row; lane owns 4 contiguous columns (float4).
// ---------------------------------------------------------------------------
__global__ __launch_bounds__(256) void k1_norm_s(const float* __restrict__ T,
                                                 float* __restrict__ inv_norm,
                                                 double* __restrict__ s) {
    __shared__ double sacc[4][DIM];
    const int lane = threadIdx.x & 63;
    const int wave = threadIdx.x >> 6;
    const int gw = blockIdx.x * 4 + wave;
    const int nw = gridDim.x * 4;
    double a0 = 0.0, a1 = 0.0, a2 = 0.0, a3 = 0.0;
    for (int row = gw; row < N_ROWS; row += nw) {
        float4 v = ((const float4*)(T + (size_t)row * DIM))[lane];
        float ss = v.x * v.x + v.y * v.y + v.z * v.z + v.w * v.w;
#pragma unroll
        for (int o = 32; o; o >>= 1) ss += __shfl_down(ss, o);
        ss = __shfl(ss, 0);
        float inv = 1.0f / fmaxf(sqrtf(ss), EPSF);
        if (lane == 0) inv_norm[row] = inv;
        a0 += (double)(v.x * inv);
        a1 += (double)(v.y * inv);
        a2 += (double)(v.z * inv);
        a3 += (double)(v.w * inv);
    }
    sacc[wave][lane * 4 + 0] = a0;
    sacc[wave][lane * 4 + 1] = a1;
    sacc[wave][lane * 4 + 2] = a2;
    sacc[wave][lane * 4 + 3] = a3;
    __syncthreads();
    const int tid = threadIdx.x;
    double t = sacc[0][tid] + sacc[1][tid] + sacc[2][tid] + sacc[3][tid];
    atomicAdd(&s[tid], t);
}

// ---------------------------------------------------------------------------
// K2b: row_sum[i] = inv_norm[i] * dot(T[i,:], s)  in fp64 (precision-critical).
// ---------------------------------------------------------------------------
__global__ __launch_bounds__(256) void k2_rowsum(const float* __restrict__ T,
                                                 const float* __restrict__ inv_norm,
                                                 const double* __restrict__ s,
                                                 double* __restrict__ rs) {
    const int lane = threadIdx.x & 63;
    const int wave = threadIdx.x >> 6;
    const int gw = blockIdx.x * 4 + wave;
    const int nw = gridDim.x * 4;
    const double s0 = s[lane * 4 + 0];
    const double s1 = s[lane * 4 + 1];
    const double s2 = s[lane * 4 + 2];
    const double s3 = s[lane * 4 + 3];
    for (int row = gw; row < N_ROWS; row += nw) {
        float4 v = ((const float4*)(T + (size_t)row * DIM))[lane];
        double d = (double)v.x * s0 + (double)v.y * s1 + (double)v.z * s2 + (double)v.w * s3;
#pragma unroll
        for (int o = 32; o; o >>= 1) d += __shfl_down(d, o);
        if (lane == 0) rs[row] = d * (double)inv_norm[row];
    }
}

// ---------------------------------------------------------------------------
// Stage-1 of M = X_hat^T @ T: 64x64 tile, 128-row K-slab (z=64 for 4 blk/CU,
// round-1 showed occupancy 15% was grid-limited), reg-staged pipelined LDS,
// fp32 partial tiles to ws (atomics write through to HBM at 16 B each).
// ---------------------------------------------------------------------------
__global__ __launch_bounds__(256) void k_gemmM_p(const float* __restrict__ T,
                                                 const float* __restrict__ inv_norm,
                                                 float* __restrict__ partials) {
    const int k0 = blockIdx.x * 64;
    const int d0 = blockIdx.y * 64;
    const int i0 = blockIdx.z * 128;
    __shared__ float As[32][68];
    __shared__ float Bs[32][68];
    const int tid = threadIdx.x;
    const int tx = tid & 15, ty = tid >> 4;
    float acc[4][4] = {};
    float4 ra[2], rb[2];
    float rinv[2];

    auto stage = [&](int ic) {
#pragma unroll
        for (int j = 0; j < 2; ++j) {
            int t = tid + 256 * j;
            int r = t >> 4, c4 = (t & 15) * 4;
            int gi = i0 + ic + r;
            rinv[j] = inv_norm[gi];
            const float* rowp = T + (size_t)gi * DIM;
            ra[j] = *(const float4*)(rowp + k0 + c4);
            rb[j] = *(const float4*)(rowp + d0 + c4);
        }
    };
    auto commit = [&]() {
#pragma unroll
        for (int j = 0; j < 2; ++j) {
            int t = tid + 256 * j;
            int r = t >> 4, c4 = (t & 15) * 4;
            float4 a = ra[j];
            float inv = rinv[j];
            a.x *= inv; a.y *= inv; a.z *= inv; a.w *= inv;
            *(float4*)&As[r][c4] = a;
            *(float4*)&Bs[r][c4] = rb[j];
        }
    };
    auto compute = [&]() {
#pragma unroll
        for (int ii = 0; ii < 32; ++ii) {
            float4 av = *(const float4*)&As[ii][ty * 4];
            float4 bv = *(const float4*)&Bs[ii][tx * 4];
            float a[4] = {av.x, av.y, av.z, av.w};
            float b[4] = {bv.x, bv.y, bv.z, bv.w};
#pragma unroll
            for (int p = 0; p < 4; ++p)
#pragma unroll
                for (int q = 0; q < 4; ++q)
                    acc[p][q] = fmaf(a[p], b[q], acc[p][q]);
        }
    };

    stage(0);
    commit();
    __syncthreads();
    for (int ic = 32; ic < 128; ic += 32) {
        stage(ic);       // next chunk's global loads in flight...
        compute();       // ...while computing current LDS chunk
        __syncthreads();
        commit();
        __syncthreads();
    }
    compute();

    float* pt = partials +
        (size_t)(blockIdx.z * 16 + blockIdx.y * 4 + blockIdx.x) * 4096;
#pragma unroll
    for (int p = 0; p < 4; ++p) {
        float4 o = make_float4(acc[p][0], acc[p][1], acc[p][2], acc[p][3]);
        *(float4*)(pt + (ty * 4 + p) * 64 + tx * 4) = o;
    }
}

// ---------------------------------------------------------------------------
// Stage-2: M[k][d] = sum over 64 z-slabs of the partial tiles (16 MB, L3-hot).
// ---------------------------------------------------------------------------
__global__ __launch_bounds__(256) void k_reduceM(const float* __restrict__ partials,
                                                 float* __restrict__ M) {
    const int g = blockIdx.x * 256 + threadIdx.x;  // 0..65535
    const int k = g >> 8, d = g & 255;
    const float* p = partials + (size_t)((d >> 6) * 4 + (k >> 6)) * 4096 +
                     (size_t)(k & 63) * 64 + (d & 63);
    float a0 = 0.f, a1 = 0.f, a2 = 0.f, a3 = 0.f;
#pragma unroll
    for (int z = 0; z < 64; z += 4) {
        a0 += p[(size_t)(z + 0) * 65536];
        a1 += p[(size_t)(z + 1) * 65536];
        a2 += p[(size_t)(z + 2) * 65536];
        a3 += p[(size_t)(z + 3) * 65536];
    }
    M[g] = (a0 + a1) + (a2 + a3);
}

// ---------------------------------------------------------------------------
// Fallback for tiny ws: atomic version (correct, slower).
// ---------------------------------------------------------------------------
__global__ __launch_bounds__(256) void k_gemmM_atomic(const float* __restrict__ T,
                                                      const float* __restrict__ inv_norm,
                                                      float* __restrict__ M) {
    const int k0 = blockIdx.x * 64;
    const int d0 = blockIdx.y * 64;
    const int i0 = blockIdx.z * 256;
    __shared__ float As[32][68];
    __shared__ float Bs[32][68];
    const int tid = threadIdx.x;
    const int tx = tid & 15, ty = tid >> 4;
    float acc[4][4] = {};
    for (int ic = 0; ic < 256; ic += 32) {
        for (int t = tid; t < 512; t += 256) {
            int r = t >> 4, c4 = (t & 15) * 4;
            int gi = i0 + ic + r;
            float inv = inv_norm[gi];
            const float* rowp = T + (size_t)gi * DIM;
            float4 a = *(const float4*)(rowp + k0 + c4);
            a.x *= inv; a.y *= inv; a.z *= inv; a.w *= inv;
            *(float4*)&As[r][c4] = a;
            *(float4*)&Bs[r][c4] = *(const float4*)(rowp + d0 + c4);
        }
        __syncthreads();
#pragma unroll
        for (int ii = 0; ii < 32; ++ii) {
            float4 av = *(const float4*)&As[ii][ty * 4];
            float4 bv = *(const float4*)&Bs[ii][tx * 4];
            float a[4] = {av.x, av.y, av.z, av.w};
            float b[4] = {bv.x, bv.y, bv.z, bv.w};
#pragma unroll
            for (int p = 0; p < 4; ++p)
#pragma unroll
                for (int q = 0; q < 4; ++q)
                    acc[p][q] = fmaf(a[p], b[q], acc[p][q]);
        }
        __syncthreads();
    }
#pragma unroll
    for (int p = 0; p < 4; ++p)
#pragma unroll
        for (int q = 0; q < 4; ++q)
            atomicAdd(&M[(size_t)(k0 + ty * 4 + p) * DIM + d0 + tx * 4 + q],
                      acc[p][q]);
}

// ---------------------------------------------------------------------------
// K3: out[i][d] = (x_hat[i,:] @ M[:,d]) / rs[i].
// 32x64 tile (i x d), grid (256,4) = 1024 blocks = 4/CU (was 2/CU @ 64x64).
// T re-reads are L3-hits (T = 8 MB << 256 MB L3). Reg-staged pipelined.
// Xs stride 34: even (float2-aligned rows) and 34 % 32 = 2 so the k-column
// transpose writes land <=2-way per bank (2-way is free, m136).
// ---------------------------------------------------------------------------
__global__ __launch_bounds__(256) void k3_out(const float* __restrict__ T,
                                              const float* __restrict__ inv_norm,
                                              const float* __restrict__ M,
                                              const double* __restrict__ rs,
                                              float* __restrict__ out) {
    const int i0 = blockIdx.x * 32;
    const int d0 = blockIdx.y * 64;
    __shared__ float Xs[32][34];  // [kk][ii]
    __shared__ float Ms[32][68];  // [kk][dd]
    const int tid = threadIdx.x;
    const int tx = tid & 15, ty = tid >> 4;
    float acc[2][4] = {};
    float4 rx, rm0, rm1;
    float rinv;

    auto stage = [&](int kc) {
        int ii = tid >> 3, k4 = (tid & 7) * 4;
        rinv = inv_norm[i0 + ii];
        rx = *(const float4*)(T + (size_t)(i0 + ii) * DIM + kc + k4);
        int kk = tid >> 4, d4 = (tid & 15) * 4;
        rm0 = *(const float4*)(M + (size_t)(kc + kk) * DIM + d0 + d4);
        rm1 = *(const float4*)(M + (size_t)(kc + kk + 16) * DIM + d0 + d4);
    };
    auto commit = [&]() {
        int ii = tid >> 3, k4 = (tid & 7) * 4;
        Xs[k4 + 0][ii] = rx.x * rinv;
        Xs[k4 + 1][ii] = rx.y * rinv;
        Xs[k4 + 2][ii] = rx.z * rinv;
        Xs[k4 + 3][ii] = rx.w * rinv;
        int kk = tid >> 4, d4 = (tid & 15) * 4;
        *(float4*)&Ms[kk][d4] = rm0;
        *(float4*)&Ms[kk + 16][d4] = rm1;
    };
    auto compute = [&]() {
#pragma unroll
        for (int kk = 0; kk < 32; ++kk) {
            float2 av = *(const float2*)&Xs[kk][ty * 2];
            float4 bv = *(const float4*)&Ms[kk][tx * 4];
            float a[2] = {av.x, av.y};
            float b[4] = {bv.x, bv.y, bv.z, bv.w};
#pragma unroll
            for (int p = 0; p < 2; ++p)
#pragma unroll
                for (int q = 0; q < 4; ++q)
                    acc[p][q] = fmaf(a[p], b[q], acc[p][q]);
        }
    };

    stage(0);
    commit();
    __syncthreads();
    for (int kc = 32; kc < 256; kc += 32) {
        stage(kc);
        compute();
        __syncthreads();
        commit();
        __syncthreads();
    }
    compute();

#pragma unroll
    for (int p = 0; p < 2; ++p) {
        int gi = i0 + ty * 2 + p;
        float invr = (float)(1.0 / rs[gi]);
        float4 o;
        o.x = acc[p][0] * invr;
        o.y = acc[p][1] * invr;
        o.z = acc[p][2] * invr;
        o.w = acc[p][3] * invr;
        *(float4*)(out + (size_t)gi * DIM + d0 + tx * 4) = o;
    }
}

// ---------------------------------------------------------------------------
extern "C" void kernel_launch(void* const* d_in, const int* in_sizes, int n_in,
                              void* d_out, int out_size, void* d_ws, size_t ws_size,
                              hipStream_t stream) {
    const float* T = (const float*)d_in[0];
    float* out = (float*)d_out;

    // workspace layout (all 16B-aligned):
    //   [0, 32768)           inv_norm  float[8192]
    //   [32768, 34816)       s         double[256]
    //   [34816, 100352)      rs        double[8192]
    //   [100352, 362496)     M         float[256*256]
    //   [362496, +16 MiB)    partials  float[64*16*4096]   (optional)
    char* ws = (char*)d_ws;
    float* inv_norm = (float*)(ws);
    double* s = (double*)(ws + 32768);
    double* rs = (double*)(ws + 34816);
    float* M = (float*)(ws + 100352);
    float* partials = (float*)(ws + 362496);
    const bool use_partials = ws_size >= (size_t)362496 + 64ull * 16 * 4096 * 4;

    hipMemsetAsync(s, 0, 256 * sizeof(double), stream);

    k1_norm_s<<<256, 256, 0, stream>>>(T, inv_norm, s);
    k2_rowsum<<<512, 256, 0, stream>>>(T, inv_norm, s, rs);
    if (use_partials) {
        k_gemmM_p<<<dim3(4, 4, 64), 256, 0, stream>>>(T, inv_norm, partials);
        k_reduceM<<<256, 256, 0, stream>>>(partials, M);
    } else {
        hipMemsetAsync(M, 0, DIM * DIM * sizeof(float), stream);
        k_gemmM_atomic<<<dim3(4, 4, 32), 256, 0, stream>>>(T, inv_norm, M);
    }
    k3_out<<<dim3(256, 4), 256, 0, stream>>>(T, inv_norm, M, rs, out);
}

// Round 4
// 104.305 us; speedup vs baseline: 1.6408x; 1.1570x over previous
//
#include <hip/hip_runtime.h>

#define N_ROWS 8192
#define DIM 256
#define EPSF 1e-8f

typedef _Float16 f16x8 __attribute__((ext_vector_type(8)));
typedef _Float16 f16x4 __attribute__((ext_vector_type(4)));
typedef float f32x4 __attribute__((ext_vector_type(4)));

// ---------------------------------------------------------------------------
// K1: per-row inv_norm (fp32) + column sums of x_hat accumulated in fp64.
// ---------------------------------------------------------------------------
__global__ __launch_bounds__(256) void k1_norm_s(const float* __restrict__ T,
                                                 float* __restrict__ inv_norm,
                                                 double* __restrict__ s) {
    __shared__ double sacc[4][DIM];
    const int lane = threadIdx.x & 63;
    const int wave = threadIdx.x >> 6;
    const int gw = blockIdx.x * 4 + wave;
    const int nw = gridDim.x * 4;
    double a0 = 0.0, a1 = 0.0, a2 = 0.0, a3 = 0.0;
    for (int row = gw; row < N_ROWS; row += nw) {
        float4 v = ((const float4*)(T + (size_t)row * DIM))[lane];
        float ss = v.x * v.x + v.y * v.y + v.z * v.z + v.w * v.w;
#pragma unroll
        for (int o = 32; o; o >>= 1) ss += __shfl_down(ss, o);
        ss = __shfl(ss, 0);
        float inv = 1.0f / fmaxf(sqrtf(ss), EPSF);
        if (lane == 0) inv_norm[row] = inv;
        a0 += (double)(v.x * inv);
        a1 += (double)(v.y * inv);
        a2 += (double)(v.z * inv);
        a3 += (double)(v.w * inv);
    }
    sacc[wave][lane * 4 + 0] = a0;
    sacc[wave][lane * 4 + 1] = a1;
    sacc[wave][lane * 4 + 2] = a2;
    sacc[wave][lane * 4 + 3] = a3;
    __syncthreads();
    const int tid = threadIdx.x;
    double t = sacc[0][tid] + sacc[1][tid] + sacc[2][tid] + sacc[3][tid];
    atomicAdd(&s[tid], t);
}

// ---------------------------------------------------------------------------
// K2: inv_rs[i] = 1 / (inv_norm[i] * dot(T[i,:], s))  in fp64 (precision-
// critical: rs can be ~6e-4 from cancellation; fp64 keeps rel err ~1e-9).
// ---------------------------------------------------------------------------
__global__ __launch_bounds__(256) void k2_rowsum(const float* __restrict__ T,
                                                 const float* __restrict__ inv_norm,
                                                 const double* __restrict__ s,
                                                 float* __restrict__ inv_rs) {
    const int lane = threadIdx.x & 63;
    const int wave = threadIdx.x >> 6;
    const int gw = blockIdx.x * 4 + wave;
    const int nw = gridDim.x * 4;
    const double s0 = s[lane * 4 + 0];
    const double s1 = s[lane * 4 + 1];
    const double s2 = s[lane * 4 + 2];
    const double s3 = s[lane * 4 + 3];
    for (int row = gw; row < N_ROWS; row += nw) {
        float4 v = ((const float4*)(T + (size_t)row * DIM))[lane];
        double d = (double)v.x * s0 + (double)v.y * s1 + (double)v.z * s2 + (double)v.w * s3;
#pragma unroll
        for (int o = 32; o; o >>= 1) d += __shfl_down(d, o);
        if (lane == 0)
            inv_rs[row] = (float)(1.0 / (d * (double)inv_norm[row]));
    }
}

// ---------------------------------------------------------------------------
// K_M: M = X_hat^T @ T via fp16 MFMA 16x16x32.  Both operands have k = row
// index i, so tiles are transpose-staged into LDS as [col][i] (stride 40
// halfs = 80 B: frag ds_read_b128 and scalar b16 staging writes are both
// <=2-way bank aliased = free).  Grid (2,2,32): 128x128 output quadrant per
// block, 256-row K-slab, fp32 partial tiles (no atomics: device-scope
// atomicAdd writes through to HBM, measured 33 MB in round 1).
// ---------------------------------------------------------------------------
__global__ __launch_bounds__(256) void k_gemmM_mfma(const float* __restrict__ T,
                                                    const float* __restrict__ inv_norm,
                                                    float* __restrict__ partials) {
    const int k0 = blockIdx.x * 128;   // M row range (X̂ column)
    const int d0 = blockIdx.y * 128;   // M col range (T column)
    const int i0 = blockIdx.z * 256;   // row slab
    __shared__ _Float16 As[128][40];   // [xcol][i]  (x̂, transposed)
    __shared__ _Float16 Bs[128][40];   // [dcol][i]  (T, transposed)
    const int tid = threadIdx.x;
    const int l = tid & 63;
    const int w = tid >> 6;
    const int wy = w >> 1, wx = w & 1;         // wave 2x2 -> 64x64 tile each
    const int lm = l & 15, lg = l >> 4;        // frag lane decomposition
    f32x4 acc[4][4] = {};
    float4 rA[4], rB[4];
    float rI[4];

    auto stage = [&](int ic) {
#pragma unroll
        for (int j = 0; j < 4; ++j) {
            int idx = tid + 256 * j;
            int i = idx & 31;
            int c4 = (idx >> 5) * 4;
            int gi = i0 + ic + i;
            rI[j] = inv_norm[gi];
            const float* rowp = T + (size_t)gi * DIM;
            rA[j] = *(const float4*)(rowp + k0 + c4);
            rB[j] = *(const float4*)(rowp + d0 + c4);
        }
    };
    auto commit = [&]() {
#pragma unroll
        for (int j = 0; j < 4; ++j) {
            int idx = tid + 256 * j;
            int i = idx & 31;
            int c4 = (idx >> 5) * 4;
            float inv = rI[j];
            As[c4 + 0][i] = (_Float16)(rA[j].x * inv);
            As[c4 + 1][i] = (_Float16)(rA[j].y * inv);
            As[c4 + 2][i] = (_Float16)(rA[j].z * inv);
            As[c4 + 3][i] = (_Float16)(rA[j].w * inv);
            Bs[c4 + 0][i] = (_Float16)rB[j].x;
            Bs[c4 + 1][i] = (_Float16)rB[j].y;
            Bs[c4 + 2][i] = (_Float16)rB[j].z;
            Bs[c4 + 3][i] = (_Float16)rB[j].w;
        }
    };
    auto compute = [&]() {
        f16x8 af[4], bf[4];
#pragma unroll
        for (int mt = 0; mt < 4; ++mt)
            af[mt] = *(const f16x8*)&As[wy * 64 + mt * 16 + lm][lg * 8];
#pragma unroll
        for (int nt = 0; nt < 4; ++nt)
            bf[nt] = *(const f16x8*)&Bs[wx * 64 + nt * 16 + lm][lg * 8];
#pragma unroll
        for (int mt = 0; mt < 4; ++mt)
#pragma unroll
            for (int nt = 0; nt < 4; ++nt)
                acc[mt][nt] = __builtin_amdgcn_mfma_f32_16x16x32_f16(
                    af[mt], bf[nt], acc[mt][nt], 0, 0, 0);
    };

    stage(0);
    commit();
    __syncthreads();
    for (int c = 1; c < 8; ++c) {
        stage(c * 32);      // next chunk's global loads in flight...
        compute();          // ...while computing current LDS chunk
        __syncthreads();
        commit();
        __syncthreads();
    }
    compute();

    // C/D frag: col = lane&15, row = (lane>>4)*4 + reg  (m89-verified)
    float* pz = partials + (size_t)blockIdx.z * 65536;
#pragma unroll
    for (int mt = 0; mt < 4; ++mt) {
        int km = k0 + wy * 64 + mt * 16 + lg * 4;
#pragma unroll
        for (int nt = 0; nt < 4; ++nt) {
            int dn = d0 + wx * 64 + nt * 16 + lm;
#pragma unroll
            for (int r = 0; r < 4; ++r)
                pz[(size_t)(km + r) * 256 + dn] = acc[mt][nt][r];
        }
    }
}

// ---------------------------------------------------------------------------
// Reduce 32 partial M slabs -> Mt (TRANSPOSED, fp16) so K3's B operand is
// k-contiguous.  Reads coalesced (adjacent tid -> adjacent d); the 2 B
// scattered writes total only 128 KB.
// ---------------------------------------------------------------------------
__global__ __launch_bounds__(256) void k_reduceM(const float* __restrict__ partials,
                                                 _Float16* __restrict__ Mt) {
    const int g = blockIdx.x * 256 + threadIdx.x;  // 0..65535
    const int k = g >> 8, d = g & 255;
    const float* p = partials + (size_t)k * 256 + d;
    float a0 = 0.f, a1 = 0.f, a2 = 0.f, a3 = 0.f;
#pragma unroll
    for (int z = 0; z < 32; z += 4) {
        a0 += p[(size_t)(z + 0) * 65536];
        a1 += p[(size_t)(z + 1) * 65536];
        a2 += p[(size_t)(z + 2) * 65536];
        a3 += p[(size_t)(z + 3) * 65536];
    }
    Mt[(size_t)d * 256 + k] = (_Float16)((a0 + a1) + (a2 + a3));
}

// ---------------------------------------------------------------------------
// K3: out[i][d] = (x_hat[i,:] @ M[:,d]) * inv_rs[i] via fp16 MFMA.
// A (x̂) and B (Mt[d][k]) are both k-contiguous: natural [row][k] LDS tiles,
// packed b64/b128 staging writes.  Grid (128,4): 64x64 tile, 2 blocks/CU.
// ---------------------------------------------------------------------------
__global__ __launch_bounds__(256) void k3_mfma(const float* __restrict__ T,
                                               const float* __restrict__ inv_norm,
                                               const _Float16* __restrict__ Mt,
                                               const float* __restrict__ inv_rs,
                                               float* __restrict__ out) {
    const int i0 = blockIdx.x * 64;
    const int d0 = blockIdx.y * 64;
    __shared__ _Float16 As[64][40];   // [i][k]
    __shared__ _Float16 Bs[64][40];   // [d][k]
    const int tid = threadIdx.x;
    const int l = tid & 63;
    const int w = tid >> 6;
    const int wy = w >> 1, wx = w & 1;         // wave 2x2 -> 32x32 tile each
    const int lm = l & 15, lg = l >> 4;
    f32x4 acc[2][2] = {};
    float4 rA[2];
    float rI[2];
    f16x8 rB;
    const int db = tid >> 2, k8 = (tid & 3) * 8;

    auto stage = [&](int kc) {
#pragma unroll
        for (int j = 0; j < 2; ++j) {
            int idx = tid + 256 * j;
            int ia = idx >> 3;
            int c4 = (idx & 7) * 4;
            int gi = i0 + ia;
            rI[j] = inv_norm[gi];
            rA[j] = *(const float4*)(T + (size_t)gi * DIM + kc + c4);
        }
        rB = *(const f16x8*)(Mt + (size_t)(d0 + db) * 256 + kc + k8);
    };
    auto commit = [&]() {
#pragma unroll
        for (int j = 0; j < 2; ++j) {
            int idx = tid + 256 * j;
            int ia = idx >> 3;
            int c4 = (idx & 7) * 4;
            float inv = rI[j];
            f16x4 h;
            h[0] = (_Float16)(rA[j].x * inv);
            h[1] = (_Float16)(rA[j].y * inv);
            h[2] = (_Float16)(rA[j].z * inv);
            h[3] = (_Float16)(rA[j].w * inv);
            *(f16x4*)&As[ia][c4] = h;
        }
        *(f16x8*)&Bs[db][k8] = rB;
    };
    auto compute = [&]() {
        f16x8 af[2], bf[2];
#pragma unroll
        for (int ti = 0; ti < 2; ++ti)
            af[ti] = *(const f16x8*)&As[wy * 32 + ti * 16 + lm][lg * 8];
#pragma unroll
        for (int tj = 0; tj < 2; ++tj)
            bf[tj] = *(const f16x8*)&Bs[wx * 32 + tj * 16 + lm][lg * 8];
#pragma unroll
        for (int ti = 0; ti < 2; ++ti)
#pragma unroll
            for (int tj = 0; tj < 2; ++tj)
                acc[ti][tj] = __builtin_amdgcn_mfma_f32_16x16x32_f16(
                    af[ti], bf[tj], acc[ti][tj], 0, 0, 0);
    };

    stage(0);
    commit();
    __syncthreads();
    for (int c = 1; c < 8; ++c) {
        stage(c * 32);
        compute();
        __syncthreads();
        commit();
        __syncthreads();
    }
    compute();

#pragma unroll
    for (int ti = 0; ti < 2; ++ti) {
#pragma unroll
        for (int r = 0; r < 4; ++r) {
            int gi = i0 + wy * 32 + ti * 16 + lg * 4 + r;
            float ir = inv_rs[gi];
#pragma unroll
            for (int tj = 0; tj < 2; ++tj)
                out[(size_t)gi * DIM + d0 + wx * 32 + tj * 16 + lm] =
                    acc[ti][tj][r] * ir;
        }
    }
}

// ---------------------------------------------------------------------------
extern "C" void kernel_launch(void* const* d_in, const int* in_sizes, int n_in,
                              void* d_out, int out_size, void* d_ws, size_t ws_size,
                              hipStream_t stream) {
    const float* T = (const float*)d_in[0];
    float* out = (float*)d_out;

    // workspace layout (harness ws is 256 MiB; we use ~8.6 MB):
    //   [0, 32768)          inv_norm  float[8192]
    //   [32768, 34816)      s         double[256]
    //   [34816, 67584)      inv_rs    float[8192]
    //   [67584, 198656)     Mt        _Float16[256*256]  (M transposed)
    //   [198656, +8 MiB)    partials  float[32*65536]
    char* ws = (char*)d_ws;
    float* inv_norm = (float*)(ws);
    double* s = (double*)(ws + 32768);
    float* inv_rs = (float*)(ws + 34816);
    _Float16* Mt = (_Float16*)(ws + 67584);
    float* partials = (float*)(ws + 198656);

    hipMemsetAsync(s, 0, 256 * sizeof(double), stream);

    k1_norm_s<<<256, 256, 0, stream>>>(T, inv_norm, s);
    k2_rowsum<<<256, 256, 0, stream>>>(T, inv_norm, s, inv_rs);
    k_gemmM_mfma<<<dim3(2, 2, 32), 256, 0, stream>>>(T, inv_norm, partials);
    k_reduceM<<<256, 256, 0, stream>>>(partials, Mt);
    k3_mfma<<<dim3(128, 4), 256, 0, stream>>>(T, inv_norm, Mt, inv_rs, out);
}